// Round 5
// baseline (256.294 us; speedup 1.0000x reference)
//
#include <hip/hip_runtime.h>
#include <math.h>

#define IMG_H 4096
#define IMG_W 4096
#define TS 64
#define HALO 3
#define TW 70              // TS + 2*HALO
#define THS 71             // th LDS row stride (odd -> conflict-free)
#define HMS 65             // hm LDS row stride (odd)
#define NBINS 4096         // linear value bins over [-4, 4]
#define NPACK 2048         // packed: two u16 counters per dword (per-block private)
#define HBLK 512           // hist grid blocks
#define CAPA 1024          // per-block speculative-candidate staging
#define CAND_MAX (1u<<22)  // candA capacity (16 MB region)
// speculative candidate bins: median bin for this input is 2047/2048 +- ~0.01 bins
#define CB_LO 2046
#define CB_HI 2049

struct SelState {
    unsigned bin;
    unsigned k_rem;
    float    median;
    unsigned flag;   // 1 = median resolved on the fast path
};

__device__ __forceinline__ unsigned f2u(float f) {
    unsigned b = __float_as_uint(f);
    unsigned mask = (unsigned)(-(int)(b >> 31)) | 0x80000000u;
    return b ^ mask;
}
__device__ __forceinline__ float u2f(unsigned u) {
    unsigned mask = (u >> 31) ? 0x80000000u : 0xFFFFFFFFu;
    return __uint_as_float(u ^ mask);
}

// Monotone non-decreasing value->bin map (identical rounding everywhere, so
// counting and compaction agree bit-exactly).
__device__ __forceinline__ int val_bin(float v) {
    float t = (v + 4.0f) * 512.0f;
    int b = (int)t;
    b = b < 0 ? 0 : b;
    b = b > (NBINS - 1) ? (NBINS - 1) : b;
    return b;
}

// ONE full read: LDS-privatized packed histogram (stored per-block, NO global
// atomics) + speculative compaction of keys in bins [CB_LO, CB_HI].
__global__ __launch_bounds__(512) void hist_compact(
    const float4* __restrict__ x4, int n4,
    unsigned* __restrict__ gh_priv,          // [HBLK][NPACK]
    unsigned* __restrict__ candA, unsigned* __restrict__ cntA)
{
    __shared__ unsigned lh[NPACK];
    __shared__ unsigned buf[CAPA];
    __shared__ unsigned lcnt, gbase;
    const int t = threadIdx.x;
    for (int i = t; i < NPACK; i += 512) lh[i] = 0;
    if (t == 0) lcnt = 0;
    __syncthreads();

    int idx = blockIdx.x * 512 + t;
    int stride = gridDim.x * 512;
    for (int i = idx; i < n4; i += stride) {
        float4 v = x4[i];
        float vs[4] = {v.x, v.y, v.z, v.w};
        #pragma unroll
        for (int j = 0; j < 4; j++) {
            int b = val_bin(vs[j]);
            atomicAdd(&lh[b >> 1], 1u << ((b & 1) * 16));
            if ((unsigned)(b - CB_LO) <= (unsigned)(CB_HI - CB_LO)) {
                unsigned p = atomicAdd(&lcnt, 1u);
                unsigned key = f2u(vs[j]);
                if (p < CAPA) buf[p] = key;
                else {
                    unsigned q = atomicAdd(cntA, 1u);
                    if (q < CAND_MAX) candA[q] = key;   // overflow -> finalize falls back
                }
            }
        }
    }
    __syncthreads();
    // private histogram store (streaming, no atomics)
    unsigned* dst = gh_priv + (size_t)blockIdx.x * NPACK;
    for (int i = t; i < NPACK; i += 512) dst[i] = lh[i];
    // candidate flush: one global atomic per block
    unsigned m = lcnt; if (m > CAPA) m = CAPA;
    if (t == 0) gbase = atomicAdd(cntA, m);
    __syncthreads();
    for (unsigned i = t; i < m; i += 512) {
        unsigned q = gbase + i;
        if (q < CAND_MAX) candA[q] = buf[i];
    }
}

// Reduce HBLK private packed histograms -> gh[4096] u32 per-bin counts.
// 64 blocks: column i = (blk&7)*256+t, block-range r = blk>>3 covers 64 blocks.
__global__ __launch_bounds__(256) void reduce_hist(
    const unsigned* __restrict__ gh_priv, unsigned* __restrict__ gh)
{
    const int i = (blockIdx.x & 7) * 256 + threadIdx.x;   // packed column 0..2047
    const int r0 = (blockIdx.x >> 3) * 64;
    unsigned lo = 0, hi = 0;
    #pragma unroll 8
    for (int b = 0; b < 64; b++) {
        unsigned d = gh_priv[(size_t)(r0 + b) * NPACK + i];
        lo += d & 0xFFFFu;
        hi += d >> 16;
    }
    atomicAdd(&gh[2 * i],     lo);
    atomicAdd(&gh[2 * i + 1], hi);
}

// Exact k-th smallest among M keys, 256 threads, 3-pass radix (11/11/10).
__device__ unsigned radix_select_256(const unsigned* __restrict__ cand, int M,
                                     unsigned kRem0)
{
    __shared__ unsigned hist[2048];
    __shared__ unsigned wsum[4];
    __shared__ unsigned s_pref, s_krem;
    const int t = threadIdx.x;
    if (t == 0) { s_pref = 0; s_krem = kRem0; }

    for (int p = 0; p < 3; p++) {
        const int shift = (p == 0) ? 21 : ((p == 1) ? 10 : 0);
        const int bits  = (p == 2) ? 10 : 11;
        const int nb    = 1 << bits;
        for (int i = t; i < nb; i += 256) hist[i] = 0;
        __syncthreads();
        const unsigned pref = s_pref;
        for (int i = t; i < M; i += 256) {
            unsigned u = cand[i];
            bool ok = (p == 0) || ((u >> ((p == 1) ? 21 : 10)) == pref);
            if (ok) atomicAdd(&hist[(u >> shift) & (unsigned)(nb - 1)], 1u);
        }
        __syncthreads();
        const int P = nb >> 8;
        unsigned cb[8];
        unsigned local = 0;
        for (int j = 0; j < P; j++) { cb[j] = hist[t * P + j]; local += cb[j]; }
        const unsigned lane = t & 63, wid = t >> 6;
        unsigned s = local;
        #pragma unroll
        for (int off = 1; off < 64; off <<= 1) {
            unsigned u = __shfl_up(s, off, 64);
            if (lane >= off) s += u;
        }
        if (lane == 63) wsum[wid] = s;
        __syncthreads();
        unsigned base = 0;
        for (unsigned w = 0; w < wid; w++) base += wsum[w];
        unsigned excl = base + s - local;
        unsigned kRem = s_krem;
        __syncthreads();
        if (kRem >= excl && kRem < excl + local) {
            unsigned cum = excl;
            for (int j = 0; j < P; j++) {
                if (kRem < cum + cb[j]) {
                    s_pref = (pref << bits) | (unsigned)(t * P + j);
                    s_krem = kRem - cum;
                    break;
                }
                cum += cb[j];
            }
        }
        __syncthreads();
    }
    return s_pref;
}

// Single block: scan gh -> rank-K bin; if it's inside the speculative window
// (and candA didn't overflow), select the median directly from candA.
// Otherwise record {bin, k_rem} for the fallback pair.
__global__ __launch_bounds__(256) void finalize_kernel(
    const unsigned* __restrict__ gh, const unsigned* __restrict__ candA,
    const unsigned* __restrict__ cntA, unsigned K, SelState* __restrict__ st)
{
    __shared__ unsigned wsum[4];
    __shared__ unsigned s_bin, s_krem, s_cumlo;
    const int t = threadIdx.x;

    unsigned cb[16];
    unsigned local = 0;
    #pragma unroll
    for (int j = 0; j < 16; j++) { cb[j] = gh[t * 16 + j]; local += cb[j]; }
    const unsigned lane = t & 63, wid = t >> 6;
    unsigned s = local;
    #pragma unroll
    for (int off = 1; off < 64; off <<= 1) {
        unsigned u = __shfl_up(s, off, 64);
        if (lane >= off) s += u;
    }
    if (lane == 63) wsum[wid] = s;
    __syncthreads();
    unsigned base = 0;
    for (unsigned w = 0; w < wid; w++) base += wsum[w];
    unsigned excl = base + s - local;
    // rank-K bin
    if (K >= excl && K < excl + local) {
        unsigned cum = excl;
        #pragma unroll
        for (int j = 0; j < 16; j++) {
            if (K < cum + cb[j]) { s_bin = (unsigned)(t * 16 + j); s_krem = K - cum; break; }
            cum += cb[j];
        }
    }
    // count of elements below bin CB_LO (owner thread: CB_LO/16)
    if (t == CB_LO / 16) {
        unsigned c = excl;
        #pragma unroll
        for (int j = 0; j < 16; j++) if (t * 16 + j < CB_LO) c += cb[j];
        s_cumlo = c;
    }
    __syncthreads();

    const unsigned bsel = s_bin;
    const unsigned M = *cntA;
    const bool direct = (bsel >= CB_LO) && (bsel <= CB_HI) && (M <= CAND_MAX);
    if (direct) {
        unsigned key = radix_select_256(candA, (int)M, K - s_cumlo);
        if (t == 0) { st->median = u2f(key); st->flag = 1; }
    } else {
        if (t == 0) { st->bin = bsel; st->k_rem = s_krem; st->flag = 0; }
    }
}

// Fallback pass (no-op when flag==1): recompact exactly bin st->bin.
__global__ __launch_bounds__(256) void fallback_compact(
    const float4* __restrict__ x4, int n4, const SelState* __restrict__ st,
    unsigned* __restrict__ candB, unsigned* __restrict__ cntB)
{
    if (st->flag) return;
    __shared__ unsigned buf[CAPA];
    __shared__ unsigned lcnt, gbase;
    const int t = threadIdx.x;
    if (t == 0) lcnt = 0;
    __syncthreads();
    const int b = (int)st->bin;
    int idx = blockIdx.x * 256 + t;
    int stride = gridDim.x * 256;
    for (int i = idx; i < n4; i += stride) {
        float4 v = x4[i];
        float vs[4] = {v.x, v.y, v.z, v.w};
        #pragma unroll
        for (int j = 0; j < 4; j++) {
            if (val_bin(vs[j]) == b) {
                unsigned p = atomicAdd(&lcnt, 1u);
                if (p < CAPA) buf[p] = f2u(vs[j]);
                else { unsigned q = atomicAdd(cntB, 1u); candB[q] = f2u(vs[j]); }
            }
        }
    }
    __syncthreads();
    unsigned m = lcnt; if (m > CAPA) m = CAPA;
    if (t == 0) gbase = atomicAdd(cntB, m);
    __syncthreads();
    for (unsigned i = t; i < m; i += 256) candB[gbase + i] = buf[i];
}

__global__ __launch_bounds__(256) void fallback_select(
    const unsigned* __restrict__ candB, const unsigned* __restrict__ cntB,
    SelState* __restrict__ st)
{
    if (st->flag) return;
    unsigned key = radix_select_256(candB, (int)*cntB, st->k_rem);
    if (threadIdx.x == 0) st->median = u2f(key);
}

// Fused threshold + 7x7 maxpool (pad=-inf) + binarize + multiply.
// 512 threads, 38KB LDS -> 4 blocks/CU -> 32 waves/CU.
__global__ __launch_bounds__(512) void nms_kernel(
    const float* __restrict__ x, float* __restrict__ out,
    const SelState* __restrict__ st)
{
    __shared__ float th[TW * THS];   // 19.4 KB
    __shared__ float hm[TW * HMS];   // 17.8 KB

    const float med = st->median;
    const float NEGINF = -__builtin_inff();
    const int gx0 = blockIdx.x * TS - HALO;
    const int gy0 = blockIdx.y * TS - HALO;

    for (int i = threadIdx.x; i < TW * TW; i += 512) {
        int r = i / TW, c = i - r * TW;
        int gy = gy0 + r, gx = gx0 + c;
        float v = NEGINF;
        if (gy >= 0 && gy < IMG_H && gx >= 0 && gx < IMG_W) {
            v = x[gy * IMG_W + gx];
            v = (v < med) ? 0.0f : v;
        }
        th[r * THS + c] = v;
    }
    __syncthreads();

    // horizontal 7-max: 560 tasks = 70 rows x 8 chunks of 8 outputs
    for (int task = threadIdx.x; task < TW * 8; task += 512) {
        int r = task % TW;
        int c0 = (task / TW) * 8;
        float w[7];
        #pragma unroll
        for (int i = 0; i < 14; i++) {
            w[i % 7] = th[r * THS + c0 + i];
            if (i >= 6) {
                float m = w[0];
                #pragma unroll
                for (int k = 1; k < 7; k++) m = fmaxf(m, w[k]);
                hm[r * HMS + c0 + i - 6] = m;
            }
        }
    }
    __syncthreads();

    // vertical 7-max + binarize*x: 64 cols x 8 chunks of 8 rows
    {
        const int c = threadIdx.x & 63;
        const int rr0 = (threadIdx.x >> 6) * 8;
        float w[7];
        #pragma unroll
        for (int i = 0; i < 14; i++) {
            w[i % 7] = hm[(rr0 + i) * HMS + c];
            if (i >= 6) {
                int R = rr0 + i - 6;
                float m = w[0];
                #pragma unroll
                for (int k = 1; k < 7; k++) m = fmaxf(m, w[k]);
                float t = th[(R + HALO) * THS + (c + HALO)];
                int gy = blockIdx.y * TS + R;
                int gx = blockIdx.x * TS + c;
                float o = 0.0f;
                if (t == m) {
                    o = (t != 0.0f) ? t : x[gy * IMG_W + gx];
                }
                out[gy * IMG_W + gx] = o;
            }
        }
    }
}

extern "C" void kernel_launch(void* const* d_in, const int* in_sizes, int n_in,
                              void* d_out, int out_size, void* d_ws, size_t ws_size,
                              hipStream_t stream)
{
    const float* x = (const float*)d_in[0];
    float* out = (float*)d_out;
    const int n = in_sizes[0];                  // 16777216
    const unsigned K = (unsigned)((n - 1) / 2); // rank of lower-middle element

    char* ws = (char*)d_ws;
    unsigned* gh      = (unsigned*)ws;                    // 4096 u32 = 16 KB
    unsigned* cntA    = (unsigned*)(ws + 16384);
    unsigned* cntB    = (unsigned*)(ws + 16388);
    SelState* st      = (SelState*)(ws + 16400);
    unsigned* gh_priv = (unsigned*)(ws + ws_size / 4);    // HBLK*8KB = 4 MB
    unsigned* candA   = (unsigned*)(ws + ws_size / 2);    // <= 16 MB

    hipMemsetAsync(d_ws, 0, 16416, stream);

    const int n4 = n / 4;
    hist_compact<<<HBLK, 512, 0, stream>>>((const float4*)x, n4, gh_priv, candA, cntA);
    reduce_hist<<<64, 256, 0, stream>>>(gh_priv, gh);
    finalize_kernel<<<1, 256, 0, stream>>>(gh, candA, cntA, K, st);
    // fallback pair: no-ops when the speculative window hit (flag==1).
    // candB = d_out (64 MB -> always large enough; nms rewrites d_out after).
    fallback_compact<<<512, 256, 0, stream>>>((const float4*)x, n4, st,
                                              (unsigned*)d_out, cntB);
    fallback_select<<<1, 256, 0, stream>>>((const unsigned*)d_out, cntB, st);

    dim3 fg(IMG_W / TS, IMG_H / TS);
    nms_kernel<<<fg, 512, 0, stream>>>(x, out, st);
}

// Round 6
// 158.502 us; speedup vs baseline: 1.6170x; 1.6170x over previous
//
#include <hip/hip_runtime.h>
#include <math.h>

#define IMG_H 4096
#define IMG_W 4096
#define TS 64
#define HALO 3
#define TW 70              // TS + 2*HALO
#define THS 71             // th LDS row stride (odd -> conflict-free)
#define HMS 65             // hm LDS row stride (odd)
#define NBINS 4096         // linear value bins over [-4, 4]
#define NPACK 2048         // packed: two u16 counters per dword (per-block private)
#define HBLK 512           // hist grid blocks
#define CAPA 1024          // per-block speculative-candidate staging
#define CAND_MAX (1u<<22)  // candA capacity (16 MB region)
// speculative window: sample median of 16.7M N(0,1) is 0 +- 3.1e-4 (1 sigma);
// window [-1/512, 1/512) = bins {2047, 2048} covers +-6.3 sigma. Exact
// fallback pair still runs if speculation misses.
#define CB_LO 2047
#define CB_HI 2048
#define RSLOT 32           // register slots per thread in finalize (32k cand cap)
#define MCAP 1024          // member buffer for the selected sub-bin
#define NSUB 2048          // linear sub-bins across the window

struct SelState {
    unsigned bin;
    unsigned k_rem;
    float    median;
    unsigned flag;   // 1 = median resolved on the fast path
};

__device__ __forceinline__ unsigned f2u(float f) {
    unsigned b = __float_as_uint(f);
    unsigned mask = (unsigned)(-(int)(b >> 31)) | 0x80000000u;
    return b ^ mask;
}
__device__ __forceinline__ float u2f(unsigned u) {
    unsigned mask = (u >> 31) ? 0x80000000u : 0xFFFFFFFFu;
    return __uint_as_float(u ^ mask);
}

// Monotone non-decreasing value->bin map (identical rounding everywhere).
__device__ __forceinline__ int val_bin(float v) {
    float t = (v + 4.0f) * 512.0f;
    int b = (int)t;
    b = b < 0 ? 0 : b;
    b = b > (NBINS - 1) ? (NBINS - 1) : b;
    return b;
}

// Monotone sub-bin map over the window value range [CB_LO, CB_HI+1) / 512 - 4.
__device__ __forceinline__ int sub_bin(float v) {
    // window lo = (CB_LO - 2048)/512, span = (CB_HI+1-CB_LO)/512
    const float lo = (float)(CB_LO - 2048) / 512.0f;
    const float scale = (float)NSUB * 512.0f / (float)(CB_HI + 1 - CB_LO);
    float t = (v - lo) * scale;
    int b = (int)t;
    b = b < 0 ? 0 : b;
    b = b > (NSUB - 1) ? (NSUB - 1) : b;
    return b;
}

// ONE full read: LDS-privatized packed histogram (stored per-block, NO global
// atomics) + speculative compaction of keys in bins [CB_LO, CB_HI].
__global__ __launch_bounds__(512) void hist_compact(
    const float4* __restrict__ x4, int n4,
    unsigned* __restrict__ gh_priv,          // [HBLK][NPACK]
    unsigned* __restrict__ candA, unsigned* __restrict__ cntA)
{
    __shared__ unsigned lh[NPACK];
    __shared__ unsigned buf[CAPA];
    __shared__ unsigned lcnt, gbase;
    const int t = threadIdx.x;
    for (int i = t; i < NPACK; i += 512) lh[i] = 0;
    if (t == 0) lcnt = 0;
    __syncthreads();

    int idx = blockIdx.x * 512 + t;
    int stride = gridDim.x * 512;
    for (int i = idx; i < n4; i += stride) {
        float4 v = x4[i];
        float vs[4] = {v.x, v.y, v.z, v.w};
        #pragma unroll
        for (int j = 0; j < 4; j++) {
            int b = val_bin(vs[j]);
            atomicAdd(&lh[b >> 1], 1u << ((b & 1) * 16));
            if ((unsigned)(b - CB_LO) <= (unsigned)(CB_HI - CB_LO)) {
                unsigned p = atomicAdd(&lcnt, 1u);
                unsigned key = f2u(vs[j]);
                if (p < CAPA) buf[p] = key;
                else {
                    unsigned q = atomicAdd(cntA, 1u);
                    if (q < CAND_MAX) candA[q] = key;
                }
            }
        }
    }
    __syncthreads();
    unsigned* dst = gh_priv + (size_t)blockIdx.x * NPACK;
    for (int i = t; i < NPACK; i += 512) dst[i] = lh[i];
    unsigned m = lcnt; if (m > CAPA) m = CAPA;
    if (t == 0) gbase = atomicAdd(cntA, m);
    __syncthreads();
    for (unsigned i = t; i < m; i += 512) {
        unsigned q = gbase + i;
        if (q < CAND_MAX) candA[q] = buf[i];
    }
}

// Reduce HBLK private packed histograms -> gh[4096] u32 per-bin counts.
__global__ __launch_bounds__(256) void reduce_hist(
    const unsigned* __restrict__ gh_priv, unsigned* __restrict__ gh)
{
    const int i = (blockIdx.x & 7) * 256 + threadIdx.x;   // packed column
    const int r0 = (blockIdx.x >> 3) * 64;
    unsigned lo = 0, hi = 0;
    #pragma unroll 8
    for (int b = 0; b < 64; b++) {
        unsigned d = gh_priv[(size_t)(r0 + b) * NPACK + i];
        lo += d & 0xFFFFu;
        hi += d >> 16;
    }
    atomicAdd(&gh[2 * i],     lo);
    atomicAdd(&gh[2 * i + 1], hi);
}

// Single block, 1024 threads. Scan gh -> rank-K bin. If inside the window:
// load all candidates into registers ONCE, linear sub-bin histogram, pick the
// rank sub-bin, gather ~13 members to LDS, O(m^2) rank-count select. Any
// anomaly -> flag=0 for the exact fallback pair.
__global__ __launch_bounds__(1024) void finalize_kernel(
    const unsigned* __restrict__ gh, const unsigned* __restrict__ candA,
    const unsigned* __restrict__ cntA, unsigned K, SelState* __restrict__ st)
{
    __shared__ unsigned hist[NSUB];
    __shared__ unsigned mem[MCAP];
    __shared__ unsigned wsum[16];
    __shared__ unsigned s_bin, s_krem, s_cumlo, s_sb, s_kr2, mcnt;
    const int t = threadIdx.x;
    const unsigned lane = t & 63, wid = t >> 6;

    // ---- gh scan: thread t covers bins [t*4, t*4+4)
    unsigned cb[4];
    unsigned local = 0;
    #pragma unroll
    for (int j = 0; j < 4; j++) { cb[j] = gh[t * 4 + j]; local += cb[j]; }
    unsigned s = local;
    #pragma unroll
    for (int off = 1; off < 64; off <<= 1) {
        unsigned u = __shfl_up(s, off, 64);
        if (lane >= off) s += u;
    }
    if (lane == 63) wsum[wid] = s;
    if (t == 0) mcnt = 0;
    __syncthreads();
    unsigned base = 0;
    for (unsigned w = 0; w < wid; w++) base += wsum[w];
    unsigned excl = base + s - local;
    if (K >= excl && K < excl + local) {
        unsigned cum = excl;
        #pragma unroll
        for (int j = 0; j < 4; j++) {
            if (K < cum + cb[j]) { s_bin = (unsigned)(t * 4 + j); s_krem = K - cum; break; }
            cum += cb[j];
        }
    }
    if (t == (CB_LO >> 2)) {      // count of elements below bin CB_LO
        unsigned c = excl;
        #pragma unroll
        for (int j = 0; j < 4; j++) if (((CB_LO >> 2) * 4 + j) < CB_LO) c += cb[j];
        s_cumlo = c;
    }
    __syncthreads();

    const unsigned bsel = s_bin;
    const unsigned M = *cntA;
    const bool direct = (bsel >= CB_LO) && (bsel <= CB_HI) && (M <= RSLOT * 1024u);

    if (!direct) {
        if (t == 0) { st->bin = bsel; st->k_rem = s_krem; st->flag = 0; }
        return;
    }

    const unsigned kRem = K - s_cumlo;   // rank within the candidate set

    // ---- load all candidates into registers (single streaming burst)
    unsigned rc[RSLOT];
    #pragma unroll
    for (int j = 0; j < RSLOT; j++) {
        int i = j * 1024 + t;
        rc[j] = (i < (int)M) ? candA[i] : 0u;
    }
    for (int i = t; i < NSUB; i += 1024) hist[i] = 0;
    __syncthreads();

    // ---- linear sub-bin histogram (near-uniform => cheap LDS atomics)
    #pragma unroll
    for (int j = 0; j < RSLOT; j++) {
        int i = j * 1024 + t;
        if (i < (int)M) atomicAdd(&hist[sub_bin(u2f(rc[j]))], 1u);
    }
    __syncthreads();

    // ---- scan sub-bins (2 per thread)
    unsigned d0 = hist[t * 2], d1 = hist[t * 2 + 1];
    unsigned loc2 = d0 + d1;
    unsigned s2 = loc2;
    #pragma unroll
    for (int off = 1; off < 64; off <<= 1) {
        unsigned u = __shfl_up(s2, off, 64);
        if (lane >= off) s2 += u;
    }
    if (lane == 63) wsum[wid] = s2;
    __syncthreads();
    unsigned base2 = 0;
    for (unsigned w = 0; w < wid; w++) base2 += wsum[w];
    unsigned excl2 = base2 + s2 - loc2;
    if (kRem >= excl2 && kRem < excl2 + loc2) {
        if (kRem < excl2 + d0) { s_sb = (unsigned)(t * 2);     s_kr2 = kRem - excl2; }
        else                   { s_sb = (unsigned)(t * 2 + 1); s_kr2 = kRem - excl2 - d0; }
    }
    __syncthreads();

    // ---- gather members of the selected sub-bin
    const int sb = (int)s_sb;
    #pragma unroll
    for (int j = 0; j < RSLOT; j++) {
        int i = j * 1024 + t;
        if (i < (int)M && sub_bin(u2f(rc[j])) == sb) {
            unsigned p = atomicAdd(&mcnt, 1u);
            if (p < MCAP) mem[p] = rc[j];
        }
    }
    __syncthreads();

    if (mcnt > MCAP) {   // adversarial clustering -> exact fallback
        if (t == 0) { st->bin = bsel; st->k_rem = s_krem; st->flag = 0; }
        return;
    }

    // ---- O(m^2) rank-count select among m members (m ~ 13)
    const unsigned m = mcnt;
    const unsigned kr2 = s_kr2;
    if ((unsigned)t < m) {
        unsigned ku = mem[t];
        unsigned c = 0, e = 0;
        for (unsigned j = 0; j < m; j++) {
            unsigned kj = mem[j];
            c += (kj < ku);
            e += (kj == ku);
        }
        if (c <= kr2 && kr2 < c + e) { st->median = u2f(ku); st->flag = 1; }
    }
}

// Exact k-th smallest among M keys, 256 threads (fallback only).
__device__ unsigned radix_select_256(const unsigned* __restrict__ cand, int M,
                                     unsigned kRem0)
{
    __shared__ unsigned hist[2048];
    __shared__ unsigned wsum[4];
    __shared__ unsigned s_pref, s_krem;
    const int t = threadIdx.x;
    if (t == 0) { s_pref = 0; s_krem = kRem0; }

    for (int p = 0; p < 3; p++) {
        const int shift = (p == 0) ? 21 : ((p == 1) ? 10 : 0);
        const int bits  = (p == 2) ? 10 : 11;
        const int nb    = 1 << bits;
        for (int i = t; i < nb; i += 256) hist[i] = 0;
        __syncthreads();
        const unsigned pref = s_pref;
        for (int i = t; i < M; i += 256) {
            unsigned u = cand[i];
            bool ok = (p == 0) || ((u >> ((p == 1) ? 21 : 10)) == pref);
            if (ok) atomicAdd(&hist[(u >> shift) & (unsigned)(nb - 1)], 1u);
        }
        __syncthreads();
        const int P = nb >> 8;
        unsigned cb[8];
        unsigned local = 0;
        for (int j = 0; j < P; j++) { cb[j] = hist[t * P + j]; local += cb[j]; }
        const unsigned lane = t & 63, wid = t >> 6;
        unsigned s = local;
        #pragma unroll
        for (int off = 1; off < 64; off <<= 1) {
            unsigned u = __shfl_up(s, off, 64);
            if (lane >= off) s += u;
        }
        if (lane == 63) wsum[wid] = s;
        __syncthreads();
        unsigned base = 0;
        for (unsigned w = 0; w < wid; w++) base += wsum[w];
        unsigned excl = base + s - local;
        unsigned kRem = s_krem;
        __syncthreads();
        if (kRem >= excl && kRem < excl + local) {
            unsigned cum = excl;
            for (int j = 0; j < P; j++) {
                if (kRem < cum + cb[j]) {
                    s_pref = (pref << bits) | (unsigned)(t * P + j);
                    s_krem = kRem - cum;
                    break;
                }
                cum += cb[j];
            }
        }
        __syncthreads();
    }
    return s_pref;
}

// Fallback pass (no-op when flag==1): recompact exactly bin st->bin.
__global__ __launch_bounds__(256) void fallback_compact(
    const float4* __restrict__ x4, int n4, const SelState* __restrict__ st,
    unsigned* __restrict__ candB, unsigned* __restrict__ cntB)
{
    if (st->flag) return;
    __shared__ unsigned buf[CAPA];
    __shared__ unsigned lcnt, gbase;
    const int t = threadIdx.x;
    if (t == 0) lcnt = 0;
    __syncthreads();
    const int b = (int)st->bin;
    int idx = blockIdx.x * 256 + t;
    int stride = gridDim.x * 256;
    for (int i = idx; i < n4; i += stride) {
        float4 v = x4[i];
        float vs[4] = {v.x, v.y, v.z, v.w};
        #pragma unroll
        for (int j = 0; j < 4; j++) {
            if (val_bin(vs[j]) == b) {
                unsigned p = atomicAdd(&lcnt, 1u);
                if (p < CAPA) buf[p] = f2u(vs[j]);
                else { unsigned q = atomicAdd(cntB, 1u); candB[q] = f2u(vs[j]); }
            }
        }
    }
    __syncthreads();
    unsigned m = lcnt; if (m > CAPA) m = CAPA;
    if (t == 0) gbase = atomicAdd(cntB, m);
    __syncthreads();
    for (unsigned i = t; i < m; i += 256) candB[gbase + i] = buf[i];
}

__global__ __launch_bounds__(256) void fallback_select(
    const unsigned* __restrict__ candB, const unsigned* __restrict__ cntB,
    SelState* __restrict__ st)
{
    if (st->flag) return;
    unsigned key = radix_select_256(candB, (int)*cntB, st->k_rem);
    if (threadIdx.x == 0) st->median = u2f(key);
}

// Fused threshold + 7x7 maxpool (pad=-inf) + binarize + multiply.
// 512 threads, 38KB LDS -> 4 blocks/CU -> 32 waves/CU.
__global__ __launch_bounds__(512) void nms_kernel(
    const float* __restrict__ x, float* __restrict__ out,
    const SelState* __restrict__ st)
{
    __shared__ float th[TW * THS];   // 19.4 KB
    __shared__ float hm[TW * HMS];   // 17.8 KB

    const float med = st->median;
    const float NEGINF = -__builtin_inff();
    const int gx0 = blockIdx.x * TS - HALO;
    const int gy0 = blockIdx.y * TS - HALO;

    for (int i = threadIdx.x; i < TW * TW; i += 512) {
        int r = i / TW, c = i - r * TW;
        int gy = gy0 + r, gx = gx0 + c;
        float v = NEGINF;
        if (gy >= 0 && gy < IMG_H && gx >= 0 && gx < IMG_W) {
            v = x[gy * IMG_W + gx];
            v = (v < med) ? 0.0f : v;
        }
        th[r * THS + c] = v;
    }
    __syncthreads();

    // horizontal 7-max: 560 tasks = 70 rows x 8 chunks of 8 outputs
    for (int task = threadIdx.x; task < TW * 8; task += 512) {
        int r = task % TW;
        int c0 = (task / TW) * 8;
        float w[7];
        #pragma unroll
        for (int i = 0; i < 14; i++) {
            w[i % 7] = th[r * THS + c0 + i];
            if (i >= 6) {
                float m = w[0];
                #pragma unroll
                for (int k = 1; k < 7; k++) m = fmaxf(m, w[k]);
                hm[r * HMS + c0 + i - 6] = m;
            }
        }
    }
    __syncthreads();

    // vertical 7-max + binarize*x: 64 cols x 8 chunks of 8 rows
    {
        const int c = threadIdx.x & 63;
        const int rr0 = (threadIdx.x >> 6) * 8;
        float w[7];
        #pragma unroll
        for (int i = 0; i < 14; i++) {
            w[i % 7] = hm[(rr0 + i) * HMS + c];
            if (i >= 6) {
                int R = rr0 + i - 6;
                float m = w[0];
                #pragma unroll
                for (int k = 1; k < 7; k++) m = fmaxf(m, w[k]);
                float t = th[(R + HALO) * THS + (c + HALO)];
                int gy = blockIdx.y * TS + R;
                int gx = blockIdx.x * TS + c;
                float o = 0.0f;
                if (t == m) {
                    o = (t != 0.0f) ? t : x[gy * IMG_W + gx];
                }
                out[gy * IMG_W + gx] = o;
            }
        }
    }
}

extern "C" void kernel_launch(void* const* d_in, const int* in_sizes, int n_in,
                              void* d_out, int out_size, void* d_ws, size_t ws_size,
                              hipStream_t stream)
{
    const float* x = (const float*)d_in[0];
    float* out = (float*)d_out;
    const int n = in_sizes[0];                  // 16777216
    const unsigned K = (unsigned)((n - 1) / 2); // rank of lower-middle element

    char* ws = (char*)d_ws;
    unsigned* gh      = (unsigned*)ws;                    // 4096 u32 = 16 KB
    unsigned* cntA    = (unsigned*)(ws + 16384);
    unsigned* cntB    = (unsigned*)(ws + 16388);
    SelState* st      = (SelState*)(ws + 16400);
    unsigned* gh_priv = (unsigned*)(ws + ws_size / 4);    // HBLK*8KB = 4 MB
    unsigned* candA   = (unsigned*)(ws + ws_size / 2);    // <= 16 MB

    hipMemsetAsync(d_ws, 0, 16416, stream);

    const int n4 = n / 4;
    hist_compact<<<HBLK, 512, 0, stream>>>((const float4*)x, n4, gh_priv, candA, cntA);
    reduce_hist<<<64, 256, 0, stream>>>(gh_priv, gh);
    finalize_kernel<<<1, 1024, 0, stream>>>(gh, candA, cntA, K, st);
    // fallback pair: no-ops when the speculative window hit (flag==1).
    fallback_compact<<<512, 256, 0, stream>>>((const float4*)x, n4, st,
                                              (unsigned*)d_out, cntB);
    fallback_select<<<1, 256, 0, stream>>>((const unsigned*)d_out, cntB, st);

    dim3 fg(IMG_W / TS, IMG_H / TS);
    nms_kernel<<<fg, 512, 0, stream>>>(x, out, st);
}

// Round 7
// 150.694 us; speedup vs baseline: 1.7008x; 1.0518x over previous
//
#include <hip/hip_runtime.h>
#include <math.h>

#define IMG_H 4096
#define IMG_W 4096
#define TS 64
#define HALO 3
#define TW 70              // TS + 2*HALO
#define THS 71             // th LDS row stride (odd -> conflict-free)
#define HMS 65             // hm LDS row stride (odd)
#define NBINS 4096         // fallback: linear value bins over [-4, 4]
#define CBLK 512           // count_compact grid blocks
#define CAPA 2048          // per-block candidate staging (expected ~51/block)
#define CAND_MAX (1u<<22)  // candA capacity
// speculative window: sample median of 16.7M N(0,1) is 0 +- 3.1e-4 (1 sigma);
// [-1/512, +1/512) covers +-6.3 sigma. Exact fallback chain guards any miss.
#define WLO (-0.001953125f)
#define WHI ( 0.001953125f)
#define RSLOT 32           // finalize register slots/thread (32k cand cap)
#define MCAP 1024          // member buffer for the selected sub-bin
#define NSUB 2048          // linear sub-bins across the window

struct SelState {
    unsigned bin;
    unsigned k_rem;
    float    median;
    unsigned flag;   // memset 0; 1 = median resolved on the fast path
};

__device__ __forceinline__ unsigned f2u(float f) {
    unsigned b = __float_as_uint(f);
    unsigned mask = (unsigned)(-(int)(b >> 31)) | 0x80000000u;
    return b ^ mask;
}
__device__ __forceinline__ float u2f(unsigned u) {
    unsigned mask = (u >> 31) ? 0x80000000u : 0xFFFFFFFFu;
    return __uint_as_float(u ^ mask);
}

// fallback-only: monotone value->bin map
__device__ __forceinline__ int val_bin(float v) {
    float t = (v + 4.0f) * 512.0f;
    int b = (int)t;
    b = b < 0 ? 0 : b;
    b = b > (NBINS - 1) ? (NBINS - 1) : b;
    return b;
}

// sub-bin map over the window [WLO, WHI): scale = NSUB / (WHI-WLO)
__device__ __forceinline__ int sub_bin(float v) {
    float t = (v - WLO) * (float)(NSUB * 256);   // 2048*256 = NSUB/(2/512)
    int b = (int)t;
    b = b < 0 ? 0 : b;
    b = b > (NSUB - 1) ? (NSUB - 1) : b;
    return b;
}

// ONE full read, ZERO histogram atomics: register count of (x < WLO) +
// LDS-staged compaction of window candidates.
__global__ __launch_bounds__(512) void count_compact(
    const float4* __restrict__ x4, int n4,
    unsigned* __restrict__ belowArr,      // [CBLK], plain stores
    unsigned* __restrict__ candA, unsigned* __restrict__ cntA)
{
    __shared__ unsigned buf[CAPA];
    __shared__ unsigned wred[8];
    __shared__ unsigned lcnt, gbase;
    const int t = threadIdx.x;
    if (t == 0) lcnt = 0;
    __syncthreads();

    unsigned below = 0;
    int idx = blockIdx.x * 512 + t;
    int stride = gridDim.x * 512;
    for (int i = idx; i < n4; i += stride) {
        float4 v = x4[i];
        float vs[4] = {v.x, v.y, v.z, v.w};
        #pragma unroll
        for (int j = 0; j < 4; j++) {
            float vv = vs[j];
            below += (vv < WLO) ? 1u : 0u;
            if (vv >= WLO && vv < WHI) {
                unsigned p = atomicAdd(&lcnt, 1u);
                unsigned key = f2u(vv);
                if (p < CAPA) buf[p] = key;
                else { unsigned q = atomicAdd(cntA, 1u); if (q < CAND_MAX) candA[q] = key; }
            }
        }
    }
    #pragma unroll
    for (int off = 32; off >= 1; off >>= 1) below += __shfl_down(below, off, 64);
    if ((t & 63) == 0) wred[t >> 6] = below;
    __syncthreads();
    if (t == 0) {
        unsigned tot = 0;
        #pragma unroll
        for (int w = 0; w < 8; w++) tot += wred[w];
        belowArr[blockIdx.x] = tot;
        gbase = atomicAdd(cntA, (lcnt > CAPA) ? CAPA : lcnt);
    }
    __syncthreads();
    unsigned m = lcnt; if (m > CAPA) m = CAPA;
    for (unsigned i = t; i < m; i += 512) {
        unsigned q = gbase + i;
        if (q < CAND_MAX) candA[q] = buf[i];
    }
}

// Single block, 1024 threads: sum belowArr; if K lands in the candidate set,
// select exactly via register-resident candidates + linear sub-bin histogram.
// Any anomaly -> leave flag=0 for the exact fallback chain.
__global__ __launch_bounds__(1024) void finalize_kernel(
    const unsigned* __restrict__ belowArr,
    const unsigned* __restrict__ candA, const unsigned* __restrict__ cntA,
    unsigned K, SelState* __restrict__ st)
{
    __shared__ unsigned hist[NSUB];
    __shared__ unsigned mem[MCAP];
    __shared__ unsigned wsum[16];
    __shared__ unsigned s_below, s_sb, s_kr2, mcnt;
    const int t = threadIdx.x;
    const unsigned lane = t & 63, wid = t >> 6;

    unsigned b = (t < CBLK) ? belowArr[t] : 0u;
    #pragma unroll
    for (int off = 32; off >= 1; off >>= 1) b += __shfl_down(b, off, 64);
    if (lane == 0) wsum[wid] = b;
    if (t == 0) mcnt = 0;
    __syncthreads();
    if (t == 0) {
        unsigned tot = 0;
        #pragma unroll
        for (int w = 0; w < 16; w++) tot += wsum[w];
        s_below = tot;
    }
    __syncthreads();

    const unsigned below = s_below;
    const unsigned M = *cntA;
    const bool direct = (K >= below) && (K - below < M) && (M <= RSLOT * 1024u);
    if (!direct) return;                 // flag stays 0 -> fallback chain

    const unsigned kRem = K - below;

    // load all candidates into registers (one streaming burst)
    unsigned rc[RSLOT];
    #pragma unroll
    for (int j = 0; j < RSLOT; j++) {
        int i = j * 1024 + t;
        rc[j] = (i < (int)M) ? candA[i] : 0u;
    }
    for (int i = t; i < NSUB; i += 1024) hist[i] = 0;
    __syncthreads();

    // linear sub-bin histogram (near-uniform -> cheap LDS atomics)
    #pragma unroll
    for (int j = 0; j < RSLOT; j++) {
        int i = j * 1024 + t;
        if (i < (int)M) atomicAdd(&hist[sub_bin(u2f(rc[j]))], 1u);
    }
    __syncthreads();

    // scan sub-bins (2/thread)
    unsigned d0 = hist[t * 2], d1 = hist[t * 2 + 1];
    unsigned loc2 = d0 + d1;
    unsigned s2 = loc2;
    #pragma unroll
    for (int off = 1; off < 64; off <<= 1) {
        unsigned u = __shfl_up(s2, off, 64);
        if (lane >= off) s2 += u;
    }
    if (lane == 63) wsum[wid] = s2;
    __syncthreads();
    unsigned base2 = 0;
    for (unsigned w = 0; w < wid; w++) base2 += wsum[w];
    unsigned excl2 = base2 + s2 - loc2;
    if (kRem >= excl2 && kRem < excl2 + loc2) {
        if (kRem < excl2 + d0) { s_sb = (unsigned)(t * 2);     s_kr2 = kRem - excl2; }
        else                   { s_sb = (unsigned)(t * 2 + 1); s_kr2 = kRem - excl2 - d0; }
    }
    __syncthreads();

    // gather members of the selected sub-bin
    const int sb = (int)s_sb;
    #pragma unroll
    for (int j = 0; j < RSLOT; j++) {
        int i = j * 1024 + t;
        if (i < (int)M && sub_bin(u2f(rc[j])) == sb) {
            unsigned p = atomicAdd(&mcnt, 1u);
            if (p < MCAP) mem[p] = rc[j];
        }
    }
    __syncthreads();
    if (mcnt > MCAP) return;             // adversarial clustering -> fallback

    // O(m^2) rank-count select among m members (m ~ 13)
    const unsigned m = mcnt;
    const unsigned kr2 = s_kr2;
    if ((unsigned)t < m) {
        unsigned ku = mem[t];
        unsigned c = 0, e = 0;
        for (unsigned j = 0; j < m; j++) {
            unsigned kj = mem[j];
            c += (kj < ku);
            e += (kj == ku);
        }
        if (c <= kr2 && kr2 < c + e) { st->median = u2f(ku); st->flag = 1; }
    }
}

// ---------------- exact fallback chain (no-ops when flag==1) ----------------

__global__ __launch_bounds__(256) void fb_hist(
    const float4* __restrict__ x4, int n4, const SelState* __restrict__ st,
    unsigned* __restrict__ gh)
{
    if (st->flag) return;
    __shared__ unsigned lh[NBINS];
    for (int i = threadIdx.x; i < NBINS; i += 256) lh[i] = 0;
    __syncthreads();
    int idx = blockIdx.x * 256 + threadIdx.x;
    int stride = gridDim.x * 256;
    for (int i = idx; i < n4; i += stride) {
        float4 v = x4[i];
        atomicAdd(&lh[val_bin(v.x)], 1u);
        atomicAdd(&lh[val_bin(v.y)], 1u);
        atomicAdd(&lh[val_bin(v.z)], 1u);
        atomicAdd(&lh[val_bin(v.w)], 1u);
    }
    __syncthreads();
    for (int i = threadIdx.x; i < NBINS; i += 256) {
        unsigned c = lh[i];
        if (c) atomicAdd(&gh[i], c);
    }
}

__global__ __launch_bounds__(1024) void fb_scan(
    const unsigned* __restrict__ gh, unsigned K, SelState* __restrict__ st)
{
    if (st->flag) return;
    __shared__ unsigned wsum[16];
    __shared__ unsigned s_bin, s_krem;
    const int t = threadIdx.x;
    const unsigned lane = t & 63, wid = t >> 6;
    unsigned cb[4];
    unsigned local = 0;
    #pragma unroll
    for (int j = 0; j < 4; j++) { cb[j] = gh[t * 4 + j]; local += cb[j]; }
    unsigned s = local;
    #pragma unroll
    for (int off = 1; off < 64; off <<= 1) {
        unsigned u = __shfl_up(s, off, 64);
        if (lane >= off) s += u;
    }
    if (lane == 63) wsum[wid] = s;
    __syncthreads();
    unsigned base = 0;
    for (unsigned w = 0; w < wid; w++) base += wsum[w];
    unsigned excl = base + s - local;
    if (K >= excl && K < excl + local) {
        unsigned cum = excl;
        #pragma unroll
        for (int j = 0; j < 4; j++) {
            if (K < cum + cb[j]) { s_bin = (unsigned)(t * 4 + j); s_krem = K - cum; break; }
            cum += cb[j];
        }
    }
    __syncthreads();
    if (t == 0) { st->bin = s_bin; st->k_rem = s_krem; }
}

__global__ __launch_bounds__(256) void fb_compact(
    const float4* __restrict__ x4, int n4, const SelState* __restrict__ st,
    unsigned* __restrict__ candB, unsigned* __restrict__ cntB)
{
    if (st->flag) return;
    __shared__ unsigned buf[CAPA];
    __shared__ unsigned lcnt, gbase;
    const int t = threadIdx.x;
    if (t == 0) lcnt = 0;
    __syncthreads();
    const int b = (int)st->bin;
    int idx = blockIdx.x * 256 + t;
    int stride = gridDim.x * 256;
    for (int i = idx; i < n4; i += stride) {
        float4 v = x4[i];
        float vs[4] = {v.x, v.y, v.z, v.w};
        #pragma unroll
        for (int j = 0; j < 4; j++) {
            if (val_bin(vs[j]) == b) {
                unsigned p = atomicAdd(&lcnt, 1u);
                if (p < CAPA) buf[p] = f2u(vs[j]);
                else { unsigned q = atomicAdd(cntB, 1u); candB[q] = f2u(vs[j]); }
            }
        }
    }
    __syncthreads();
    unsigned m = lcnt; if (m > CAPA) m = CAPA;
    if (t == 0) gbase = atomicAdd(cntB, m);
    __syncthreads();
    for (unsigned i = t; i < m; i += 256) candB[gbase + i] = buf[i];
}

__global__ __launch_bounds__(256) void fb_select(
    const unsigned* __restrict__ candB, const unsigned* __restrict__ cntB,
    SelState* __restrict__ st)
{
    if (st->flag) return;
    __shared__ unsigned hist[2048];
    __shared__ unsigned wsum[4];
    __shared__ unsigned s_pref, s_krem;
    const int t = threadIdx.x;
    const int M = (int)*cntB;
    if (t == 0) { s_pref = 0; s_krem = st->k_rem; }

    for (int p = 0; p < 3; p++) {
        const int shift = (p == 0) ? 21 : ((p == 1) ? 10 : 0);
        const int bits  = (p == 2) ? 10 : 11;
        const int nb    = 1 << bits;
        for (int i = t; i < nb; i += 256) hist[i] = 0;
        __syncthreads();
        const unsigned pref = s_pref;
        for (int i = t; i < M; i += 256) {
            unsigned u = candB[i];
            bool ok = (p == 0) || ((u >> ((p == 1) ? 21 : 10)) == pref);
            if (ok) atomicAdd(&hist[(u >> shift) & (unsigned)(nb - 1)], 1u);
        }
        __syncthreads();
        const int P = nb >> 8;
        unsigned cb[8];
        unsigned local = 0;
        for (int j = 0; j < P; j++) { cb[j] = hist[t * P + j]; local += cb[j]; }
        const unsigned lane = t & 63, wid = t >> 6;
        unsigned s = local;
        #pragma unroll
        for (int off = 1; off < 64; off <<= 1) {
            unsigned u = __shfl_up(s, off, 64);
            if (lane >= off) s += u;
        }
        if (lane == 63) wsum[wid] = s;
        __syncthreads();
        unsigned base = 0;
        for (unsigned w = 0; w < wid; w++) base += wsum[w];
        unsigned excl = base + s - local;
        unsigned kRem = s_krem;
        __syncthreads();
        if (kRem >= excl && kRem < excl + local) {
            unsigned cum = excl;
            for (int j = 0; j < P; j++) {
                if (kRem < cum + cb[j]) {
                    s_pref = (pref << bits) | (unsigned)(t * P + j);
                    s_krem = kRem - cum;
                    break;
                }
                cum += cb[j];
            }
        }
        __syncthreads();
    }
    if (t == 0) st->median = u2f(s_pref);
}

// -------- fused threshold + 7x7 maxpool (pad=-inf) + binarize + multiply ----
// 512 threads, 38KB LDS -> 4 blocks/CU. Stage via aligned float4 loads.
__global__ __launch_bounds__(512) void nms_kernel(
    const float* __restrict__ x, float* __restrict__ out,
    const SelState* __restrict__ st)
{
    __shared__ float th[TW * THS];   // 19.4 KB
    __shared__ float hm[TW * HMS];   // 17.8 KB

    const float med = st->median;
    const float NEGINF = -__builtin_inff();
    const int bx = blockIdx.x, by = blockIdx.y;
    const int gy0 = by * TS - HALO;
    const int gcol0 = bx * TS - 4;       // float4-aligned staging start

    // stage: 70 rows x 18 float4 (covers cols gcol0..gcol0+71 => th cols -1..70)
    for (int task = threadIdx.x; task < TW * 18; task += 512) {
        int r = task / 18, q = task - r * 18;
        int gy = gy0 + r;
        int gxb = gcol0 + q * 4;
        bool rowok = (gy >= 0 && gy < IMG_H);
        float vs[4];
        if (rowok && gxb >= 0 && gxb + 4 <= IMG_W) {
            float4 v = *(const float4*)&x[gy * IMG_W + gxb];
            vs[0] = v.x; vs[1] = v.y; vs[2] = v.z; vs[3] = v.w;
        } else if (rowok) {
            #pragma unroll
            for (int cmp = 0; cmp < 4; cmp++) {
                int gx = gxb + cmp;
                vs[cmp] = (gx >= 0 && gx < IMG_W) ? x[gy * IMG_W + gx] : NEGINF;
            }
        } else {
            vs[0] = vs[1] = vs[2] = vs[3] = NEGINF;
        }
        #pragma unroll
        for (int cmp = 0; cmp < 4; cmp++) {
            int c = q * 4 - 1 + cmp;
            if ((unsigned)c < (unsigned)TW) {
                float v = vs[cmp];
                // threshold only in-bounds values; OOB stays -inf
                v = (v == NEGINF) ? v : ((v < med) ? 0.0f : v);
                th[r * THS + c] = v;
            }
        }
    }
    __syncthreads();

    // horizontal 7-max: 560 tasks = 70 rows x 8 chunks of 8 outputs
    for (int task = threadIdx.x; task < TW * 8; task += 512) {
        int r = task % TW;
        int c0 = (task / TW) * 8;
        float w[7];
        #pragma unroll
        for (int i = 0; i < 14; i++) {
            w[i % 7] = th[r * THS + c0 + i];
            if (i >= 6) {
                float m = w[0];
                #pragma unroll
                for (int k = 1; k < 7; k++) m = fmaxf(m, w[k]);
                hm[r * HMS + c0 + i - 6] = m;
            }
        }
    }
    __syncthreads();

    // vertical 7-max + binarize*x: 64 cols x 8 chunks of 8 rows
    {
        const int c = threadIdx.x & 63;
        const int rr0 = (threadIdx.x >> 6) * 8;
        float w[7];
        #pragma unroll
        for (int i = 0; i < 14; i++) {
            w[i % 7] = hm[(rr0 + i) * HMS + c];
            if (i >= 6) {
                int R = rr0 + i - 6;
                float m = w[0];
                #pragma unroll
                for (int k = 1; k < 7; k++) m = fmaxf(m, w[k]);
                float t = th[(R + HALO) * THS + (c + HALO)];
                int gy = by * TS + R;
                int gx = bx * TS + c;
                float o = 0.0f;
                if (t == m) {
                    // t != 0: t IS the original x. t == 0: whole window
                    // sub-median (rare) -> reread x for sign preservation.
                    o = (t != 0.0f) ? t : x[gy * IMG_W + gx];
                }
                out[gy * IMG_W + gx] = o;
            }
        }
    }
}

extern "C" void kernel_launch(void* const* d_in, const int* in_sizes, int n_in,
                              void* d_out, int out_size, void* d_ws, size_t ws_size,
                              hipStream_t stream)
{
    const float* x = (const float*)d_in[0];
    float* out = (float*)d_out;
    const int n = in_sizes[0];                  // 16777216
    const unsigned K = (unsigned)((n - 1) / 2); // rank of lower-middle element

    char* ws = (char*)d_ws;
    unsigned* gh       = (unsigned*)ws;                 // 4096 u32 (fallback)
    unsigned* cntA     = (unsigned*)(ws + 16384);
    unsigned* cntB     = (unsigned*)(ws + 16388);
    SelState* st       = (SelState*)(ws + 16400);       // flag memset to 0
    unsigned* belowArr = (unsigned*)(ws + 16640);       // [CBLK], fully rewritten
    unsigned* candA    = (unsigned*)(ws + ws_size / 2); // 16 MB region

    hipMemsetAsync(d_ws, 0, 16416, stream);

    const int n4 = n / 4;
    count_compact<<<CBLK, 512, 0, stream>>>((const float4*)x, n4, belowArr, candA, cntA);
    finalize_kernel<<<1, 1024, 0, stream>>>(belowArr, candA, cntA, K, st);
    // exact fallback chain: no-ops when flag==1 (candB = d_out scratch)
    fb_hist<<<512, 256, 0, stream>>>((const float4*)x, n4, st, gh);
    fb_scan<<<1, 1024, 0, stream>>>(gh, K, st);
    fb_compact<<<512, 256, 0, stream>>>((const float4*)x, n4, st, (unsigned*)d_out, cntB);
    fb_select<<<1, 256, 0, stream>>>((const unsigned*)d_out, cntB, st);

    dim3 fg(IMG_W / TS, IMG_H / TS);
    nms_kernel<<<fg, 512, 0, stream>>>(x, out, st);
}

// Round 8
// 149.186 us; speedup vs baseline: 1.7180x; 1.0101x over previous
//
#include <hip/hip_runtime.h>
#include <math.h>

#define IMG_H 4096
#define IMG_W 4096
#define TS 64
#define HALO 3
#define TW 70              // TS + 2*HALO
#define THS 71             // th LDS row stride (odd -> conflict-free)
#define HMS 65             // hm LDS row stride (odd)
#define NBINS 4096         // fallback: linear value bins over [-4, 4]
#define CBLK 1024          // count_compact grid blocks
#define CAPA 1024          // per-block candidate staging (expected ~26/block)
#define CAND_MAX (1u<<22)  // candA capacity
// speculative window: sample median of 16.7M N(0,1) is 0 +- 3.1e-4 (1 sigma);
// [-1/512, +1/512) covers +-6.3 sigma. Exact single-kernel fallback guards it.
#define WLO (-0.001953125f)
#define WHI ( 0.001953125f)
#define RSLOT 32           // finalize register slots/thread (32k cand cap)
#define MCAP 1024          // member buffer for the selected sub-bin
#define NSUB 2048          // linear sub-bins across the window

struct SelState {
    unsigned bin;
    unsigned k_rem;
    float    median;
    unsigned flag;   // memset 0; 1 = median resolved on the fast path
};

__device__ __forceinline__ unsigned f2u(float f) {
    unsigned b = __float_as_uint(f);
    unsigned mask = (unsigned)(-(int)(b >> 31)) | 0x80000000u;
    return b ^ mask;
}
__device__ __forceinline__ float u2f(unsigned u) {
    unsigned mask = (u >> 31) ? 0x80000000u : 0xFFFFFFFFu;
    return __uint_as_float(u ^ mask);
}

// fallback-only: monotone value->bin map
__device__ __forceinline__ int val_bin(float v) {
    float t = (v + 4.0f) * 512.0f;
    int b = (int)t;
    b = b < 0 ? 0 : b;
    b = b > (NBINS - 1) ? (NBINS - 1) : b;
    return b;
}

// sub-bin map over the window [WLO, WHI)
__device__ __forceinline__ int sub_bin(float v) {
    float t = (v - WLO) * (float)(NSUB * 256);
    int b = (int)t;
    b = b < 0 ? 0 : b;
    b = b > (NSUB - 1) ? (NSUB - 1) : b;
    return b;
}

// ONE full read, zero histogram atomics: register count of (x < WLO) +
// LDS-staged compaction of window candidates.
__global__ __launch_bounds__(512) void count_compact(
    const float4* __restrict__ x4, int n4,
    unsigned* __restrict__ belowArr,      // [CBLK], plain stores
    unsigned* __restrict__ candA, unsigned* __restrict__ cntA)
{
    __shared__ unsigned buf[CAPA];
    __shared__ unsigned wred[8];
    __shared__ unsigned lcnt, gbase;
    const int t = threadIdx.x;
    if (t == 0) lcnt = 0;
    __syncthreads();

    unsigned below = 0;
    int idx = blockIdx.x * 512 + t;
    int stride = gridDim.x * 512;
    for (int i = idx; i < n4; i += stride) {
        float4 v = x4[i];
        float vs[4] = {v.x, v.y, v.z, v.w};
        #pragma unroll
        for (int j = 0; j < 4; j++) {
            float vv = vs[j];
            below += (vv < WLO) ? 1u : 0u;
            if (vv >= WLO && vv < WHI) {
                unsigned p = atomicAdd(&lcnt, 1u);
                unsigned key = f2u(vv);
                if (p < CAPA) buf[p] = key;
                else { unsigned q = atomicAdd(cntA, 1u); if (q < CAND_MAX) candA[q] = key; }
            }
        }
    }
    #pragma unroll
    for (int off = 32; off >= 1; off >>= 1) below += __shfl_down(below, off, 64);
    if ((t & 63) == 0) wred[t >> 6] = below;
    __syncthreads();
    if (t == 0) {
        unsigned tot = 0;
        #pragma unroll
        for (int w = 0; w < 8; w++) tot += wred[w];
        belowArr[blockIdx.x] = tot;
        gbase = atomicAdd(cntA, (lcnt > CAPA) ? CAPA : lcnt);
    }
    __syncthreads();
    unsigned m = lcnt; if (m > CAPA) m = CAPA;
    for (unsigned i = t; i < m; i += 512) {
        unsigned q = gbase + i;
        if (q < CAND_MAX) candA[q] = buf[i];
    }
}

// Single block, 1024 threads: sum belowArr; if K lands in the candidate set,
// select exactly via register-resident candidates + linear sub-bin histogram.
// Any anomaly -> leave flag=0 for the exact fallback kernel.
__global__ __launch_bounds__(1024) void finalize_kernel(
    const unsigned* __restrict__ belowArr,
    const unsigned* __restrict__ candA, const unsigned* __restrict__ cntA,
    unsigned K, SelState* __restrict__ st)
{
    __shared__ unsigned hist[NSUB];
    __shared__ unsigned mem[MCAP];
    __shared__ unsigned wsum[16];
    __shared__ unsigned s_below, s_sb, s_kr2, mcnt;
    const int t = threadIdx.x;
    const unsigned lane = t & 63, wid = t >> 6;

    unsigned b = (t < CBLK) ? belowArr[t] : 0u;
    #pragma unroll
    for (int off = 32; off >= 1; off >>= 1) b += __shfl_down(b, off, 64);
    if (lane == 0) wsum[wid] = b;
    if (t == 0) mcnt = 0;
    __syncthreads();
    if (t == 0) {
        unsigned tot = 0;
        #pragma unroll
        for (int w = 0; w < 16; w++) tot += wsum[w];
        s_below = tot;
    }
    __syncthreads();

    const unsigned below = s_below;
    const unsigned M = *cntA;
    const bool direct = (K >= below) && (K - below < M) && (M <= RSLOT * 1024u);
    if (!direct) return;                 // flag stays 0 -> fallback kernel

    const unsigned kRem = K - below;

    // load all candidates into registers (one streaming burst)
    unsigned rc[RSLOT];
    #pragma unroll
    for (int j = 0; j < RSLOT; j++) {
        int i = j * 1024 + t;
        rc[j] = (i < (int)M) ? candA[i] : 0u;
    }
    for (int i = t; i < NSUB; i += 1024) hist[i] = 0;
    __syncthreads();

    // linear sub-bin histogram (near-uniform -> cheap LDS atomics)
    #pragma unroll
    for (int j = 0; j < RSLOT; j++) {
        int i = j * 1024 + t;
        if (i < (int)M) atomicAdd(&hist[sub_bin(u2f(rc[j]))], 1u);
    }
    __syncthreads();

    // scan sub-bins (2/thread)
    unsigned d0 = hist[t * 2], d1 = hist[t * 2 + 1];
    unsigned loc2 = d0 + d1;
    unsigned s2 = loc2;
    #pragma unroll
    for (int off = 1; off < 64; off <<= 1) {
        unsigned u = __shfl_up(s2, off, 64);
        if (lane >= off) s2 += u;
    }
    if (lane == 63) wsum[wid] = s2;
    __syncthreads();
    unsigned base2 = 0;
    for (unsigned w = 0; w < wid; w++) base2 += wsum[w];
    unsigned excl2 = base2 + s2 - loc2;
    if (kRem >= excl2 && kRem < excl2 + loc2) {
        if (kRem < excl2 + d0) { s_sb = (unsigned)(t * 2);     s_kr2 = kRem - excl2; }
        else                   { s_sb = (unsigned)(t * 2 + 1); s_kr2 = kRem - excl2 - d0; }
    }
    __syncthreads();

    // gather members of the selected sub-bin
    const int sb = (int)s_sb;
    #pragma unroll
    for (int j = 0; j < RSLOT; j++) {
        int i = j * 1024 + t;
        if (i < (int)M && sub_bin(u2f(rc[j])) == sb) {
            unsigned p = atomicAdd(&mcnt, 1u);
            if (p < MCAP) mem[p] = rc[j];
        }
    }
    __syncthreads();
    if (mcnt > MCAP) return;             // adversarial clustering -> fallback

    // O(m^2) rank-count select among m members (m ~ 13)
    const unsigned m = mcnt;
    const unsigned kr2 = s_kr2;
    if ((unsigned)t < m) {
        unsigned ku = mem[t];
        unsigned c = 0, e = 0;
        for (unsigned j = 0; j < m; j++) {
            unsigned kj = mem[j];
            c += (kj < ku);
            e += (kj == ku);
        }
        if (c <= kr2 && kr2 < c + e) { st->median = u2f(ku); st->flag = 1; }
    }
}

// ---- exact fallback, ONE single-block kernel (runs fully only if flag==0) --
// Slow (~1 ms) but exact for ANY input distribution; in practice it costs one
// dispatch + one flag load. Uses candB (= d_out scratch) for bin members.
__global__ __launch_bounds__(1024) void fb_exact(
    const float4* __restrict__ x4, int n4, unsigned K,
    unsigned* __restrict__ candB, SelState* __restrict__ st)
{
    if (st->flag) return;
    __shared__ unsigned lh[NBINS];       // 16 KB
    __shared__ unsigned wsum[16];
    __shared__ unsigned s_bin, s_krem, s_m, s_pref, s_kr;
    const int t = threadIdx.x;
    const unsigned lane = t & 63, wid = t >> 6;

    // pass A: full-input histogram (single block, grid-stride)
    for (int i = t; i < NBINS; i += 1024) lh[i] = 0;
    __syncthreads();
    for (int i = t; i < n4; i += 1024) {
        float4 v = x4[i];
        atomicAdd(&lh[val_bin(v.x)], 1u);
        atomicAdd(&lh[val_bin(v.y)], 1u);
        atomicAdd(&lh[val_bin(v.z)], 1u);
        atomicAdd(&lh[val_bin(v.w)], 1u);
    }
    __syncthreads();

    // scan 4 bins/thread -> rank-K bin
    {
        unsigned cb[4];
        unsigned local = 0;
        #pragma unroll
        for (int j = 0; j < 4; j++) { cb[j] = lh[t * 4 + j]; local += cb[j]; }
        unsigned s = local;
        #pragma unroll
        for (int off = 1; off < 64; off <<= 1) {
            unsigned u = __shfl_up(s, off, 64);
            if (lane >= off) s += u;
        }
        if (lane == 63) wsum[wid] = s;
        __syncthreads();
        unsigned base = 0;
        for (unsigned w = 0; w < wid; w++) base += wsum[w];
        unsigned excl = base + s - local;
        if (K >= excl && K < excl + local) {
            unsigned cum = excl;
            #pragma unroll
            for (int j = 0; j < 4; j++) {
                if (K < cum + cb[j]) { s_bin = (unsigned)(t * 4 + j); s_krem = K - cum; break; }
                cum += cb[j];
            }
        }
        if (t == 0) s_m = 0;
        __syncthreads();
    }

    // pass B: compact the selected bin's keys to candB (global scatter)
    {
        const int b = (int)s_bin;
        for (int i = t; i < n4; i += 1024) {
            float4 v = x4[i];
            float vs[4] = {v.x, v.y, v.z, v.w};
            #pragma unroll
            for (int j = 0; j < 4; j++) {
                if (val_bin(vs[j]) == b) {
                    unsigned p = atomicAdd(&s_m, 1u);
                    candB[p] = f2u(vs[j]);
                }
            }
        }
        __syncthreads();
    }

    // pass C: 3-pass radix select over the M bin members
    const int M = (int)s_m;
    if (t == 0) { s_pref = 0; s_kr = s_krem; }
    for (int p = 0; p < 3; p++) {
        const int shift = (p == 0) ? 21 : ((p == 1) ? 10 : 0);
        const int bits  = (p == 2) ? 10 : 11;
        const int nb    = 1 << bits;
        for (int i = t; i < nb; i += 1024) lh[i] = 0;
        __syncthreads();
        const unsigned pref = s_pref;
        for (int i = t; i < M; i += 1024) {
            unsigned u = candB[i];
            bool ok = (p == 0) || ((u >> ((p == 1) ? 21 : 10)) == pref);
            if (ok) atomicAdd(&lh[(u >> shift) & (unsigned)(nb - 1)], 1u);
        }
        __syncthreads();
        const int P = nb >> 10;           // 2 or 1 bins/thread
        unsigned c0 = lh[t * (P ? P : 1)];
        unsigned c1 = (P == 2) ? lh[t * 2 + 1] : 0u;
        unsigned valid = (P >= 1) || (t < nb);
        if (P == 0) { c0 = (t < nb) ? lh[t] : 0u; c1 = 0u; }
        unsigned local = valid ? (c0 + c1) : 0u;
        unsigned s = local;
        #pragma unroll
        for (int off = 1; off < 64; off <<= 1) {
            unsigned u = __shfl_up(s, off, 64);
            if (lane >= off) s += u;
        }
        if (lane == 63) wsum[wid] = s;
        __syncthreads();
        unsigned base = 0;
        for (unsigned w = 0; w < wid; w++) base += wsum[w];
        unsigned excl = base + s - local;
        unsigned kRem = s_kr;
        __syncthreads();
        if (kRem >= excl && kRem < excl + local) {
            if (P == 2) {
                if (kRem < excl + c0) { s_pref = (pref << bits) | (unsigned)(t * 2);     s_kr = kRem - excl; }
                else                  { s_pref = (pref << bits) | (unsigned)(t * 2 + 1); s_kr = kRem - excl - c0; }
            } else {
                s_pref = (pref << bits) | (unsigned)t;
                s_kr = kRem - excl;
            }
        }
        __syncthreads();
    }
    if (t == 0) st->median = u2f(s_pref);
}

// -------- fused threshold + 7x7 maxpool (pad=-inf) + binarize + multiply ----
// 512 threads, 38KB LDS -> 4 blocks/CU. Stage via aligned float4 loads.
__global__ __launch_bounds__(512) void nms_kernel(
    const float* __restrict__ x, float* __restrict__ out,
    const SelState* __restrict__ st)
{
    __shared__ float th[TW * THS];   // 19.4 KB
    __shared__ float hm[TW * HMS];   // 17.8 KB

    const float med = st->median;
    const float NEGINF = -__builtin_inff();
    const int bx = blockIdx.x, by = blockIdx.y;
    const int gy0 = by * TS - HALO;
    const int gcol0 = bx * TS - 4;       // float4-aligned staging start

    // stage: 70 rows x 18 float4 (covers cols gcol0..gcol0+71 => th cols -1..70)
    for (int task = threadIdx.x; task < TW * 18; task += 512) {
        int r = task / 18, q = task - r * 18;
        int gy = gy0 + r;
        int gxb = gcol0 + q * 4;
        bool rowok = (gy >= 0 && gy < IMG_H);
        float vs[4];
        if (rowok && gxb >= 0 && gxb + 4 <= IMG_W) {
            float4 v = *(const float4*)&x[gy * IMG_W + gxb];
            vs[0] = v.x; vs[1] = v.y; vs[2] = v.z; vs[3] = v.w;
        } else if (rowok) {
            #pragma unroll
            for (int cmp = 0; cmp < 4; cmp++) {
                int gx = gxb + cmp;
                vs[cmp] = (gx >= 0 && gx < IMG_W) ? x[gy * IMG_W + gx] : NEGINF;
            }
        } else {
            vs[0] = vs[1] = vs[2] = vs[3] = NEGINF;
        }
        #pragma unroll
        for (int cmp = 0; cmp < 4; cmp++) {
            int c = q * 4 - 1 + cmp;
            if ((unsigned)c < (unsigned)TW) {
                float v = vs[cmp];
                v = (v == NEGINF) ? v : ((v < med) ? 0.0f : v);
                th[r * THS + c] = v;
            }
        }
    }
    __syncthreads();

    // horizontal 7-max: 560 tasks = 70 rows x 8 chunks of 8 outputs
    for (int task = threadIdx.x; task < TW * 8; task += 512) {
        int r = task % TW;
        int c0 = (task / TW) * 8;
        float w[7];
        #pragma unroll
        for (int i = 0; i < 14; i++) {
            w[i % 7] = th[r * THS + c0 + i];
            if (i >= 6) {
                float m = w[0];
                #pragma unroll
                for (int k = 1; k < 7; k++) m = fmaxf(m, w[k]);
                hm[r * HMS + c0 + i - 6] = m;
            }
        }
    }
    __syncthreads();

    // vertical 7-max + binarize*x: 64 cols x 8 chunks of 8 rows
    {
        const int c = threadIdx.x & 63;
        const int rr0 = (threadIdx.x >> 6) * 8;
        float w[7];
        #pragma unroll
        for (int i = 0; i < 14; i++) {
            w[i % 7] = hm[(rr0 + i) * HMS + c];
            if (i >= 6) {
                int R = rr0 + i - 6;
                float m = w[0];
                #pragma unroll
                for (int k = 1; k < 7; k++) m = fmaxf(m, w[k]);
                float t = th[(R + HALO) * THS + (c + HALO)];
                int gy = by * TS + R;
                int gx = bx * TS + c;
                float o = 0.0f;
                if (t == m) {
                    o = (t != 0.0f) ? t : x[gy * IMG_W + gx];
                }
                out[gy * IMG_W + gx] = o;
            }
        }
    }
}

extern "C" void kernel_launch(void* const* d_in, const int* in_sizes, int n_in,
                              void* d_out, int out_size, void* d_ws, size_t ws_size,
                              hipStream_t stream)
{
    const float* x = (const float*)d_in[0];
    float* out = (float*)d_out;
    const int n = in_sizes[0];                  // 16777216
    const unsigned K = (unsigned)((n - 1) / 2); // rank of lower-middle element

    char* ws = (char*)d_ws;
    unsigned* cntA     = (unsigned*)ws;                 // 4 B
    SelState* st       = (SelState*)(ws + 16);          // flag memset to 0
    unsigned* belowArr = (unsigned*)(ws + 256);         // [CBLK], fully rewritten
    unsigned* candA    = (unsigned*)(ws + ws_size / 2); // 16 MB region

    hipMemsetAsync(d_ws, 0, 32, stream);

    const int n4 = n / 4;
    count_compact<<<CBLK, 512, 0, stream>>>((const float4*)x, n4, belowArr, candA, cntA);
    finalize_kernel<<<1, 1024, 0, stream>>>(belowArr, candA, cntA, K, st);
    // exact single-kernel fallback: no-op when flag==1 (candB = d_out scratch)
    fb_exact<<<1, 1024, 0, stream>>>((const float4*)x, n4, K, (unsigned*)d_out, st);

    dim3 fg(IMG_W / TS, IMG_H / TS);
    nms_kernel<<<fg, 512, 0, stream>>>(x, out, st);
}